// Round 1
// baseline (11878.996 us; speedup 1.0000x reference)
//
#include <hip/hip_runtime.h>
#include <hip/hip_bf16.h>
#include <cstdint>
#include <cstddef>

// Problem constants (match reference)
static constexpr int B   = 4;
static constexpr int CIN = 256;
static constexpr int T   = 100;   // time / start dim
static constexpr int D   = 100;   // duration dim
static constexpr int S   = 32;    // num_sample bins
static constexpr int C1  = 128;   // reduced channels
static constexpr int O3  = 512;   // conv3d output channels
static constexpr int DU  = D * T; // 10000

// ---------------------------------------------------------------------------
// w3dT[s][c][o] = w3d[o][c][s]
__global__ void kTransW3(const float* __restrict__ w3d, float* __restrict__ w3dT) {
    int tid = blockIdx.x * blockDim.x + threadIdx.x;   // 32*128*512 = 2097152
    int o = tid & 511;
    int c = (tid >> 9) & 127;
    int s = tid >> 16;
    w3dT[tid] = w3d[(o * 128 + c) * 32 + s];
}

// w2dT[o][k] = w2d[k][o]
__global__ void kTransW2(const float* __restrict__ w2d, float* __restrict__ w2dT) {
    int tid = blockIdx.x * blockDim.x + threadIdx.x;   // 512*128 = 65536
    int k = tid & 127;
    int o = tid >> 7;
    w2dT[tid] = w2d[k * 512 + o];
}

// ---------------------------------------------------------------------------
// h[b][o][t] = relu(brd[o] + sum_{c,tap} wrd[o][c][tap] * x[b][c][t+tap-1])
__global__ void kConv1d(const float* __restrict__ x, const float* __restrict__ wrd,
                        const float* __restrict__ brd, float* __restrict__ h) {
    __shared__ float wl[CIN * 3];
    int b = blockIdx.x >> 7;
    int o = blockIdx.x & 127;
    for (int i = threadIdx.x; i < CIN * 3; i += blockDim.x)
        wl[i] = wrd[o * CIN * 3 + i];
    __syncthreads();
    int t = threadIdx.x;
    if (t >= T) return;
    float acc = brd[o];
    const float* xb = x + (size_t)b * CIN * T;
    for (int c = 0; c < CIN; ++c) {
        float xm = (t > 0)     ? xb[c * T + t - 1] : 0.f;
        float x0 =               xb[c * T + t];
        float xp = (t < T - 1) ? xb[c * T + t + 1] : 0.f;
        acc = fmaf(wl[c * 3 + 0], xm, acc);
        acc = fmaf(wl[c * 3 + 1], x0, acc);
        acc = fmaf(wl[c * 3 + 2], xp, acc);
    }
    h[((size_t)b * C1 + o) * T + t] = fmaxf(acc, 0.f);
}

// ---------------------------------------------------------------------------
// Q[b][s][t][o] = sum_c w3dT[s][c][o] * h[b][c][t]
__global__ void kQ(const float* __restrict__ w3dT, const float* __restrict__ h,
                   float* __restrict__ Q) {
    int blk = blockIdx.x;            // 4*32*4 = 512 blocks
    int tc = blk & 3;
    int s  = (blk >> 2) & 31;
    int b  = blk >> 7;
    int o  = threadIdx.x;            // 512
    int t0 = tc * 25;
    float acc[25];
#pragma unroll
    for (int j = 0; j < 25; ++j) acc[j] = 0.f;
    const float* wp = w3dT + (size_t)s * 128 * 512 + o;
    const float* hp = h + (size_t)b * C1 * T + t0;
    for (int c = 0; c < C1; ++c) {
        float w = wp[(size_t)c * 512];
#pragma unroll
        for (int j = 0; j < 25; ++j)
            acc[j] = fmaf(w, hp[c * T + j], acc[j]);   // hp uniform -> scalar loads
    }
    float* qp = Q + (((size_t)b * S + s) * T + t0) * 512 + o;
#pragma unroll
    for (int j = 0; j < 25; ++j) qp[(size_t)j * 512] = acc[j];
}

// ---------------------------------------------------------------------------
// m3[b][du][o] = relu(b3d[o] + sum_{s,t} mask[t][s][d][u] * Q[b][s][t][o])
// Sparse-by-window: for each s-bin, nonzero t lie in a conservatively-computed
// window (exact construction arithmetic + slack); actual weights read from mask.
__global__ void kM3(const float* __restrict__ Q, const float* __restrict__ mask,
                    const float* __restrict__ b3d, float* __restrict__ m3) {
    int blk = blockIdx.x;            // 4*100*7 = 2800
    int ut = blk % 7;
    int d  = (blk / 7) % 100;
    int b  = blk / 700;
    int o  = threadIdx.x;            // 512
    int u0 = ut * 16;
    float bias = b3d[o];
    float acc[16];
#pragma unroll
    for (int i = 0; i < 16; ++i) acc[i] = bias;

    double step = (2.0 * d + 1.0) / 95.0;      // plen/(num_sample*perbin-1)
    double xoff = -0.5 * (d + 1.0);            // -ratio*clen
    const float* Qb = Q + (size_t)b * S * T * 512 + o;
    bool full = (u0 + 16 <= 100);

    for (int s = 0; s < S; ++s) {
        double pmin = (double)u0 + xoff + step * (3 * s);
        double pmax = (double)(u0 + 15) + xoff + step * (3 * s + 2);
        int t0 = (int)floor(pmin) - 1; if (t0 < 0)  t0 = 0;
        int t1 = (int)ceil(pmax) + 1;  if (t1 > 99) t1 = 99;
        const float* Qs = Qb + (size_t)s * T * 512;
        for (int t = t0; t <= t1; ++t) {
            float qv = Qs[(size_t)t * 512];
            const float* mrow = mask + (((size_t)t * S + s) * D + d) * T + u0;
            if (full) {
#pragma unroll
                for (int uu = 0; uu < 16; ++uu)
                    acc[uu] = fmaf(mrow[uu], qv, acc[uu]);
            } else {
#pragma unroll
                for (int uu = 0; uu < 16; ++uu)
                    if (u0 + uu < 100)
                        acc[uu] = fmaf(mrow[uu], qv, acc[uu]);
            }
        }
    }
#pragma unroll
    for (int uu = 0; uu < 16; ++uu) {
        int u = u0 + uu;
        if (u < 100)
            m3[((size_t)b * DU + d * 100 + u) * 512 + o] = fmaxf(acc[uu], 0.f);
    }
}

// ---------------------------------------------------------------------------
// m2[b][du][k] = relu(b2d[k] + sum_o m3[b][du][o] * w2d[k][o])
// Register-tiled GEMM: block = 64 du x 128 k, thread = 4 du x 8 k.
__global__ void kM2(const float* __restrict__ m3, const float* __restrict__ w2dT,
                    const float* __restrict__ b2d, float* __restrict__ m2) {
    __shared__ float mA[64][65];       // [du_local][o_local], padded
    __shared__ float wB[64 * 128];     // [o_local][k]
    int blk  = blockIdx.x;             // 4 * 157
    int tile = blk % 157;
    int b    = blk / 157;
    int du0  = tile * 64;
    int tid  = threadIdx.x;
    int tk   = tid & 15;
    int tdu  = tid >> 4;
    float acc[4][8];
#pragma unroll
    for (int i = 0; i < 4; ++i)
#pragma unroll
        for (int j = 0; j < 8; ++j) acc[i][j] = 0.f;

    for (int oc = 0; oc < 8; ++oc) {
        __syncthreads();
        for (int it = 0; it < 16; ++it) {
            int idx = it * 256 + tid;              // 4096
            int j = idx >> 6, op = idx & 63;
            int du = du0 + j;
            mA[j][op] = (du < DU) ? m3[((size_t)b * DU + du) * 512 + oc * 64 + op] : 0.f;
        }
        for (int it = 0; it < 32; ++it) {
            int idx = it * 256 + tid;              // 8192
            wB[idx] = w2dT[(size_t)(oc * 64 + (idx >> 7)) * 128 + (idx & 127)];
        }
        __syncthreads();
        for (int op = 0; op < 64; ++op) {
            float aa[4];
#pragma unroll
            for (int i = 0; i < 4; ++i) aa[i] = mA[tdu * 4 + i][op];
            const float4* bp = (const float4*)&wB[op * 128 + tk * 8];
            float4 b0 = bp[0], b1 = bp[1];
            float bb[8] = {b0.x, b0.y, b0.z, b0.w, b1.x, b1.y, b1.z, b1.w};
#pragma unroll
            for (int i = 0; i < 4; ++i)
#pragma unroll
                for (int j = 0; j < 8; ++j)
                    acc[i][j] = fmaf(aa[i], bb[j], acc[i][j]);
        }
    }
#pragma unroll
    for (int i = 0; i < 4; ++i) {
        int du = du0 + tdu * 4 + i;
        if (du < DU) {
#pragma unroll
            for (int j = 0; j < 8; ++j) {
                int k = tk * 8 + j;
                m2[((size_t)b * DU + du) * 128 + k] = fmaxf(acc[i][j] + b2d[k], 0.f);
            }
        }
    }
}

// ---------------------------------------------------------------------------
// 3x3 conv, 128->128, channels-last [b][d][u][c]; block = (b,d) row.
__global__ void kConv3x3(const float* __restrict__ fin, const float* __restrict__ wf,
                         const float* __restrict__ bf, float* __restrict__ fout) {
    __shared__ float inl[3 * 102 * 9];   // [dy][upos][c], pitch 9 (bank-conflict-free)
    __shared__ float wl[72 * 128];       // [(c*9+tap)][k]
    int b = blockIdx.x / 100;
    int d = blockIdx.x % 100;
    int tid = threadIdx.x;
    int tk = tid & 15;
    int tu = tid >> 4;
    float acc[7][8];
#pragma unroll
    for (int j = 0; j < 7; ++j)
#pragma unroll
        for (int kk = 0; kk < 8; ++kk) acc[j][kk] = 0.f;

    for (int cc = 0; cc < 16; ++cc) {    // 16 chunks of 8 channels
        __syncthreads();
        // stage input: 3 rows x 102 upos x 8 c
        for (int it = 0; it < 10; ++it) {
            int idx = it * 256 + tid;
            if (idx < 3 * 102 * 8) {
                int c  = idx & 7;
                int up = (idx >> 3) % 102;
                int dy = idx / (102 * 8);
                int dr = d - 1 + dy;
                int su = up - 1;
                float v = 0.f;
                if (dr >= 0 && dr < 100 && su >= 0 && su < 100)
                    v = fin[((size_t)b * DU + dr * 100 + su) * 128 + cc * 8 + c];
                inl[(dy * 102 + up) * 9 + c] = v;
            }
        }
        // stage weights: wl[(c*9+tap)*128 + k] = wf[k][cc*8+c][tap]
        for (int it = 0; it < 36; ++it) {
            int idx = it * 256 + tid;            // 9216 = 72*128
            int k = idx & 127, r = idx >> 7;
            wl[(size_t)r * 128 + k] = wf[(size_t)k * 1152 + cc * 72 + r];
        }
        __syncthreads();
#pragma unroll
        for (int c = 0; c < 8; ++c) {
#pragma unroll
            for (int tap = 0; tap < 9; ++tap) {
                int dy = tap / 3, dx = tap % 3;
                const float4* wp = (const float4*)&wl[(c * 9 + tap) * 128 + tk * 8];
                float4 w0 = wp[0], w1 = wp[1];
                float wv[8] = {w0.x, w0.y, w0.z, w0.w, w1.x, w1.y, w1.z, w1.w};
#pragma unroll
                for (int j = 0; j < 7; ++j) {
                    int u = tu + 16 * j;
                    if (u < 100) {
                        float a = inl[(dy * 102 + u + dx) * 9 + c];
#pragma unroll
                        for (int kk = 0; kk < 8; ++kk)
                            acc[j][kk] = fmaf(a, wv[kk], acc[j][kk]);
                    }
                }
            }
        }
    }
#pragma unroll
    for (int j = 0; j < 7; ++j) {
        int u = tu + 16 * j;
        if (u < 100) {
            size_t base = ((size_t)b * DU + d * 100 + u) * 128 + tk * 8;
#pragma unroll
            for (int kk = 0; kk < 8; ++kk)
                fout[base + kk] = fmaxf(acc[j][kk] + bf[tk * 8 + kk], 0.f);
        }
    }
}

// ---------------------------------------------------------------------------
// out[b][k2][d][u] = sigmoid(bf3[k2] + sum_c f2[b][du][c]*wf3[k2][c])
__global__ void kHead(const float* __restrict__ f2, const float* __restrict__ wf3,
                      const float* __restrict__ bf3, float* __restrict__ out) {
    int gid = blockIdx.x * blockDim.x + threadIdx.x;
    if (gid >= B * DU) return;
    int b  = gid / DU;
    int du = gid % DU;
    const float* fp = f2 + (size_t)gid * 128;
    float d0 = 0.f, d1 = 0.f;
    for (int c = 0; c < 128; ++c) {
        float v = fp[c];
        d0 = fmaf(v, wf3[c], d0);
        d1 = fmaf(v, wf3[128 + c], d1);
    }
    d0 += bf3[0];
    d1 += bf3[1];
    out[((size_t)b * 2 + 0) * DU + du] = 1.f / (1.f + expf(-d0));
    out[((size_t)b * 2 + 1) * DU + du] = 1.f / (1.f + expf(-d1));
}

// ---------------------------------------------------------------------------
extern "C" void kernel_launch(void* const* d_in, const int* in_sizes, int n_in,
                              void* d_out, int out_size, void* d_ws, size_t ws_size,
                              hipStream_t stream) {
    const float* x    = (const float*)d_in[0];
    const float* wrd  = (const float*)d_in[1];
    const float* brd  = (const float*)d_in[2];
    const float* w3d  = (const float*)d_in[3];
    const float* b3d  = (const float*)d_in[4];
    const float* w2d  = (const float*)d_in[5];
    const float* b2d  = (const float*)d_in[6];
    const float* wf1  = (const float*)d_in[7];
    const float* bf1  = (const float*)d_in[8];
    const float* wf2  = (const float*)d_in[9];
    const float* bf2  = (const float*)d_in[10];
    const float* wf3  = (const float*)d_in[11];
    const float* bf3  = (const float*)d_in[12];
    const float* mask = (const float*)d_in[13];

    float* ws   = (float*)d_ws;
    float* h    = ws;                       // 51,200
    float* w3dT = h    + 51200;             // 2,097,152
    float* w2dT = w3dT + 2097152;           // 65,536
    float* Q    = w2dT + 65536;             // 6,553,600
    float* m3L  = Q    + 6553600;           // 20,480,000
    float* m2L  = m3L  + 20480000;          // 5,120,000
    float* f1   = m3L;                      // alias: m3 dead after kM2
    float* f2   = m3L + 5120000;            // alias

    kTransW3<<<8192, 256, 0, stream>>>(w3d, w3dT);
    kTransW2<<<256, 256, 0, stream>>>(w2d, w2dT);
    kConv1d<<<B * C1, 128, 0, stream>>>(x, wrd, brd, h);
    kQ<<<B * S * 4, 512, 0, stream>>>(w3dT, h, Q);
    kM3<<<B * D * 7, 512, 0, stream>>>(Q, mask, b3d, m3L);
    kM2<<<B * 157, 256, 0, stream>>>(m3L, w2dT, b2d, m2L);
    kConv3x3<<<B * D, 256, 0, stream>>>(m2L, wf1, bf1, f1);
    kConv3x3<<<B * D, 256, 0, stream>>>(f1, wf2, bf2, f2);
    kHead<<<(B * DU + 255) / 256, 256, 0, stream>>>(f2, wf3, bf3, (float*)d_out);
}

// Round 2
// 10924.070 us; speedup vs baseline: 1.0874x; 1.0874x over previous
//
#include <hip/hip_runtime.h>
#include <hip/hip_bf16.h>
#include <cstdint>
#include <cstddef>

// Problem constants (match reference)
static constexpr int B   = 4;
static constexpr int CIN = 256;
static constexpr int T   = 100;   // time / start dim
static constexpr int D   = 100;   // duration dim
static constexpr int S   = 32;    // num_sample bins
static constexpr int C1  = 128;   // reduced channels
static constexpr int O3  = 512;   // conv3d output channels
static constexpr int DU  = D * T; // 10000

// ---------------------------------------------------------------------------
// w3dT[s][c][o] = w3d[o][c][s]
__global__ void kTransW3(const float* __restrict__ w3d, float* __restrict__ w3dT) {
    int tid = blockIdx.x * blockDim.x + threadIdx.x;   // 32*128*512 = 2097152
    int o = tid & 511;
    int c = (tid >> 9) & 127;
    int s = tid >> 16;
    w3dT[tid] = w3d[(o * 128 + c) * 32 + s];
}

// w2dT[o][k] = w2d[k][o]
__global__ void kTransW2(const float* __restrict__ w2d, float* __restrict__ w2dT) {
    int tid = blockIdx.x * blockDim.x + threadIdx.x;   // 512*128 = 65536
    int k = tid & 127;
    int o = tid >> 7;
    w2dT[tid] = w2d[k * 512 + o];
}

// wfT[(c*9+tap)*128 + k] = wf[k*1152 + c*9 + tap]   (147456 elements)
__global__ void kTransWf(const float* __restrict__ wf, float* __restrict__ wfT) {
    int tid = blockIdx.x * blockDim.x + threadIdx.x;
    int k = tid & 127;
    int r = tid >> 7;        // 0..1151  (= c*9+tap)
    wfT[tid] = wf[(size_t)k * 1152 + r];
}

// ---------------------------------------------------------------------------
// h[b][o][t] = relu(brd[o] + sum_{c,tap} wrd[o][c][tap] * x[b][c][t+tap-1])
__global__ void kConv1d(const float* __restrict__ x, const float* __restrict__ wrd,
                        const float* __restrict__ brd, float* __restrict__ h) {
    __shared__ float wl[CIN * 3];
    int b = blockIdx.x >> 7;
    int o = blockIdx.x & 127;
    for (int i = threadIdx.x; i < CIN * 3; i += blockDim.x)
        wl[i] = wrd[o * CIN * 3 + i];
    __syncthreads();
    int t = threadIdx.x;
    if (t >= T) return;
    float acc = brd[o];
    const float* xb = x + (size_t)b * CIN * T;
    for (int c = 0; c < CIN; ++c) {
        float xm = (t > 0)     ? xb[c * T + t - 1] : 0.f;
        float x0 =               xb[c * T + t];
        float xp = (t < T - 1) ? xb[c * T + t + 1] : 0.f;
        acc = fmaf(wl[c * 3 + 0], xm, acc);
        acc = fmaf(wl[c * 3 + 1], x0, acc);
        acc = fmaf(wl[c * 3 + 2], xp, acc);
    }
    h[((size_t)b * C1 + o) * T + t] = fmaxf(acc, 0.f);
}

// ---------------------------------------------------------------------------
// Q[b][s][t][o] = sum_c w3dT[s][c][o] * h[b][c][t]
__global__ __launch_bounds__(512, 4)
void kQ(const float* __restrict__ w3dT, const float* __restrict__ h,
        float* __restrict__ Q) {
    int blk = blockIdx.x;            // 4*32*4 = 512 blocks
    int tc = blk & 3;
    int s  = (blk >> 2) & 31;
    int b  = blk >> 7;
    int o  = threadIdx.x;            // 512
    int t0 = tc * 25;
    float acc[25];
#pragma unroll
    for (int j = 0; j < 25; ++j) acc[j] = 0.f;
    const float* wp = w3dT + (size_t)s * 128 * 512 + o;
    const float* hp = h + (size_t)b * C1 * T + t0;
    for (int c = 0; c < C1; ++c) {
        float w = wp[(size_t)c * 512];
#pragma unroll
        for (int j = 0; j < 25; ++j)
            acc[j] = fmaf(w, hp[c * T + j], acc[j]);   // hp uniform -> scalar loads
    }
    float* qp = Q + (((size_t)b * S + s) * T + t0) * 512 + o;
#pragma unroll
    for (int j = 0; j < 25; ++j) qp[(size_t)j * 512] = acc[j];
}

// ---------------------------------------------------------------------------
// m3[b][du][o] = relu(b3d[o] + sum_{s,t} mask[t][s][d][u] * Q[b][s][t][o])
// Sparse-by-window: for each s-bin, nonzero t lie in a conservatively-computed
// window (exact construction arithmetic + slack); actual weights read from mask.
__global__ __launch_bounds__(512, 2)
void kM3(const float* __restrict__ Q, const float* __restrict__ mask,
         const float* __restrict__ b3d, float* __restrict__ m3) {
    int blk = blockIdx.x;            // 4*100*7 = 2800
    int ut = blk % 7;
    int d  = (blk / 7) % 100;
    int b  = blk / 700;
    int o  = threadIdx.x;            // 512
    int u0 = ut * 16;
    float bias = b3d[o];
    float acc[16];
#pragma unroll
    for (int i = 0; i < 16; ++i) acc[i] = bias;

    double step = (2.0 * d + 1.0) / 95.0;      // plen/(num_sample*perbin-1)
    double xoff = -0.5 * (d + 1.0);            // -ratio*clen
    const float* Qb = Q + (size_t)b * S * T * 512 + o;
    bool full = (u0 + 16 <= 100);

    for (int s = 0; s < S; ++s) {
        double pmin = (double)u0 + xoff + step * (3 * s);
        double pmax = (double)(u0 + 15) + xoff + step * (3 * s + 2);
        int t0 = (int)floor(pmin) - 1; if (t0 < 0)  t0 = 0;
        int t1 = (int)ceil(pmax) + 1;  if (t1 > 99) t1 = 99;
        const float* Qs = Qb + (size_t)s * T * 512;
        for (int t = t0; t <= t1; ++t) {
            float qv = Qs[(size_t)t * 512];
            const float* mrow = mask + (((size_t)t * S + s) * D + d) * T + u0;
            if (full) {
#pragma unroll
                for (int uu = 0; uu < 16; ++uu)
                    acc[uu] = fmaf(mrow[uu], qv, acc[uu]);
            } else {
#pragma unroll
                for (int uu = 0; uu < 16; ++uu)
                    if (u0 + uu < 100)
                        acc[uu] = fmaf(mrow[uu], qv, acc[uu]);
            }
        }
    }
#pragma unroll
    for (int uu = 0; uu < 16; ++uu) {
        int u = u0 + uu;
        if (u < 100)
            m3[((size_t)b * DU + d * 100 + u) * 512 + o] = fmaxf(acc[uu], 0.f);
    }
}

// ---------------------------------------------------------------------------
// m2[b][du][k] = relu(b2d[k] + sum_o m3[b][du][o] * w2d[k][o])
// Register-tiled GEMM: block = 64 du x 128 k, thread = 4 du x 8 k.
__global__ __launch_bounds__(256, 4)
void kM2(const float* __restrict__ m3, const float* __restrict__ w2dT,
         const float* __restrict__ b2d, float* __restrict__ m2) {
    __shared__ float mA[64][65];       // [du_local][o_local], padded
    __shared__ float wB[64 * 128];     // [o_local][k]
    int blk  = blockIdx.x;             // 4 * 157
    int tile = blk % 157;
    int b    = blk / 157;
    int du0  = tile * 64;
    int tid  = threadIdx.x;
    int tk   = tid & 15;
    int tdu  = tid >> 4;
    float acc[4][8];
#pragma unroll
    for (int i = 0; i < 4; ++i)
#pragma unroll
        for (int j = 0; j < 8; ++j) acc[i][j] = 0.f;

    for (int oc = 0; oc < 8; ++oc) {
        __syncthreads();
        for (int it = 0; it < 16; ++it) {
            int idx = it * 256 + tid;              // 4096
            int j = idx >> 6, op = idx & 63;
            int du = du0 + j;
            mA[j][op] = (du < DU) ? m3[((size_t)b * DU + du) * 512 + oc * 64 + op] : 0.f;
        }
        for (int it = 0; it < 32; ++it) {
            int idx = it * 256 + tid;              // 8192
            wB[idx] = w2dT[(size_t)(oc * 64 + (idx >> 7)) * 128 + (idx & 127)];
        }
        __syncthreads();
        for (int op = 0; op < 64; ++op) {
            float aa[4];
#pragma unroll
            for (int i = 0; i < 4; ++i) aa[i] = mA[tdu * 4 + i][op];
            const float4* bp = (const float4*)&wB[op * 128 + tk * 8];
            float4 b0 = bp[0], b1 = bp[1];
            float bb[8] = {b0.x, b0.y, b0.z, b0.w, b1.x, b1.y, b1.z, b1.w};
#pragma unroll
            for (int i = 0; i < 4; ++i)
#pragma unroll
                for (int j = 0; j < 8; ++j)
                    acc[i][j] = fmaf(aa[i], bb[j], acc[i][j]);
        }
    }
#pragma unroll
    for (int i = 0; i < 4; ++i) {
        int du = du0 + tdu * 4 + i;
        if (du < DU) {
#pragma unroll
            for (int j = 0; j < 8; ++j) {
                int k = tk * 8 + j;
                m2[((size_t)b * DU + du) * 128 + k] = fmaxf(acc[i][j] + b2d[k], 0.f);
            }
        }
    }
}

// ---------------------------------------------------------------------------
// 3x3 conv, 128->128, channels-last [b][d][u][c]; block = one (b,d) row.
// 512 threads: tk = tid&15 -> 8-channel output group, tu = tid>>4 -> u rows
// (u = tu + 32j, j=0..3). acc[4][8] = 32 regs -> no spill.
// Weights pre-transposed: wfT[(c*9+tap)*128 + k], staged per 8-c chunk
// as a contiguous coalesced copy.
__global__ __launch_bounds__(512, 2)
void kConv3x3(const float* __restrict__ fin, const float* __restrict__ wfT,
              const float* __restrict__ bf, float* __restrict__ fout) {
    __shared__ float wl[72 * 128];       // 36.9 KB: [(c_local*9+tap)][k]
    __shared__ float inl[3 * 102 * 8];   // 9.8 KB:  [dy][u+1][c_local]
    int b = blockIdx.x / 100;
    int d = blockIdx.x % 100;
    int tid = threadIdx.x;
    int tk = tid & 15;
    int tu = tid >> 4;                   // 0..31
    float acc[4][8];
#pragma unroll
    for (int j = 0; j < 4; ++j)
#pragma unroll
        for (int kk = 0; kk < 8; ++kk) acc[j][kk] = 0.f;

    for (int cc = 0; cc < 16; ++cc) {    // 16 chunks of 8 input channels
        __syncthreads();
        // stage weights: contiguous 9216-float copy (fully coalesced)
        for (int i = tid; i < 9216; i += 512)
            wl[i] = wfT[(size_t)cc * 9216 + i];
        // stage input halo tile: 3 rows x 102 upos x 8 c
        for (int i = tid; i < 2448; i += 512) {
            int c  = i & 7;
            int up = (i >> 3) % 102;
            int dy = (i >> 3) / 102;
            int dr = d - 1 + dy;
            int su = up - 1;
            float v = 0.f;
            if (dr >= 0 && dr < 100 && su >= 0 && su < 100)
                v = fin[((size_t)b * DU + dr * 100 + su) * 128 + cc * 8 + c];
            inl[(dy * 102 + up) * 8 + c] = v;
        }
        __syncthreads();
#pragma unroll
        for (int c = 0; c < 8; ++c) {
#pragma unroll
            for (int tap = 0; tap < 9; ++tap) {
                int dy = tap / 3, dx = tap % 3;
                const float4* wp = (const float4*)&wl[(c * 9 + tap) * 128 + tk * 8];
                float4 w0 = wp[0], w1 = wp[1];
                float wv[8] = {w0.x, w0.y, w0.z, w0.w, w1.x, w1.y, w1.z, w1.w};
#pragma unroll
                for (int j = 0; j < 4; ++j) {
                    int u = tu + 32 * j;
                    if (u < 100) {       // uniform per (wave, j): no divergence
                        float a = inl[(dy * 102 + u + dx) * 8 + c];
#pragma unroll
                        for (int kk = 0; kk < 8; ++kk)
                            acc[j][kk] = fmaf(a, wv[kk], acc[j][kk]);
                    }
                }
            }
        }
    }
#pragma unroll
    for (int j = 0; j < 4; ++j) {
        int u = tu + 32 * j;
        if (u < 100) {
            size_t base = ((size_t)b * DU + d * 100 + u) * 128 + tk * 8;
#pragma unroll
            for (int kk = 0; kk < 8; ++kk)
                fout[base + kk] = fmaxf(acc[j][kk] + bf[tk * 8 + kk], 0.f);
        }
    }
}

// ---------------------------------------------------------------------------
// out[b][k2][d][u] = sigmoid(bf3[k2] + sum_c f2[b][du][c]*wf3[k2][c])
__global__ void kHead(const float* __restrict__ f2, const float* __restrict__ wf3,
                      const float* __restrict__ bf3, float* __restrict__ out) {
    int gid = blockIdx.x * blockDim.x + threadIdx.x;
    if (gid >= B * DU) return;
    int b  = gid / DU;
    int du = gid % DU;
    const float* fp = f2 + (size_t)gid * 128;
    float d0 = 0.f, d1 = 0.f;
    for (int c = 0; c < 128; ++c) {
        float v = fp[c];
        d0 = fmaf(v, wf3[c], d0);
        d1 = fmaf(v, wf3[128 + c], d1);
    }
    d0 += bf3[0];
    d1 += bf3[1];
    out[((size_t)b * 2 + 0) * DU + du] = 1.f / (1.f + expf(-d0));
    out[((size_t)b * 2 + 1) * DU + du] = 1.f / (1.f + expf(-d1));
}

// ---------------------------------------------------------------------------
extern "C" void kernel_launch(void* const* d_in, const int* in_sizes, int n_in,
                              void* d_out, int out_size, void* d_ws, size_t ws_size,
                              hipStream_t stream) {
    const float* x    = (const float*)d_in[0];
    const float* wrd  = (const float*)d_in[1];
    const float* brd  = (const float*)d_in[2];
    const float* w3d  = (const float*)d_in[3];
    const float* b3d  = (const float*)d_in[4];
    const float* w2d  = (const float*)d_in[5];
    const float* b2d  = (const float*)d_in[6];
    const float* wf1  = (const float*)d_in[7];
    const float* bf1  = (const float*)d_in[8];
    const float* wf2  = (const float*)d_in[9];
    const float* bf2  = (const float*)d_in[10];
    const float* wf3  = (const float*)d_in[11];
    const float* bf3  = (const float*)d_in[12];
    const float* mask = (const float*)d_in[13];

    float* ws   = (float*)d_ws;
    float* h    = ws;                       // 51,200
    float* w3dT = h    + 51200;             // 2,097,152
    float* w2dT = w3dT + 2097152;           // 65,536
    float* Q    = w2dT + 65536;             // 6,553,600
    float* m3L  = Q    + 6553600;           // 20,480,000
    float* m2L  = m3L  + 20480000;          // 5,120,000
    float* f1   = m3L;                      // alias: m3 dead after kM2
    float* f2   = m3L + 5120000;            // alias
    float* wfT1 = m3L + 10240000;           // alias tail of m3 region (147,456)
    float* wfT2 = wfT1 + 147456;            // 147,456

    kTransW3<<<8192, 256, 0, stream>>>(w3d, w3dT);
    kTransW2<<<256, 256, 0, stream>>>(w2d, w2dT);
    kConv1d<<<B * C1, 128, 0, stream>>>(x, wrd, brd, h);
    kQ<<<B * S * 4, 512, 0, stream>>>(w3dT, h, Q);
    kM3<<<B * D * 7, 512, 0, stream>>>(Q, mask, b3d, m3L);
    kM2<<<B * 157, 256, 0, stream>>>(m3L, w2dT, b2d, m2L);
    // weight transposes for the 3x3 convs (m3 region is dead now -> tail reuse)
    kTransWf<<<576, 256, 0, stream>>>(wf1, wfT1);
    kTransWf<<<576, 256, 0, stream>>>(wf2, wfT2);
    kConv3x3<<<B * D, 512, 0, stream>>>(m2L, wfT1, bf1, f1);
    kConv3x3<<<B * D, 512, 0, stream>>>(f1, wfT2, bf2, f2);
    kHead<<<(B * DU + 255) / 256, 256, 0, stream>>>(f2, wf3, bf3, (float*)d_out);
}

// Round 3
// 1494.751 us; speedup vs baseline: 7.9471x; 7.3083x over previous
//
#include <hip/hip_runtime.h>
#include <hip/hip_bf16.h>
#include <cstdint>
#include <cstddef>

// Problem constants (match reference)
static constexpr int B   = 4;
static constexpr int CIN = 256;
static constexpr int T   = 100;   // time / start dim
static constexpr int D   = 100;   // duration dim
static constexpr int S   = 32;    // num_sample bins
static constexpr int C1  = 128;   // reduced channels
static constexpr int DU  = D * T; // 10000

// ---------------------------------------------------------------------------
// w3dT[s][c][o] = w3d[o][c][s]
__global__ void kTransW3(const float* __restrict__ w3d, float* __restrict__ w3dT) {
    int tid = blockIdx.x * blockDim.x + threadIdx.x;   // 32*128*512 = 2097152
    int o = tid & 511;
    int c = (tid >> 9) & 127;
    int s = tid >> 16;
    w3dT[tid] = w3d[(o * 128 + c) * 32 + s];
}

// w2dT[o][k] = w2d[k][o]
__global__ void kTransW2(const float* __restrict__ w2d, float* __restrict__ w2dT) {
    int tid = blockIdx.x * blockDim.x + threadIdx.x;   // 512*128 = 65536
    int k = tid & 127;
    int o = tid >> 7;
    w2dT[tid] = w2d[k * 512 + o];
}

// wfT[(c*9+tap)*128 + k] = wf[k*1152 + c*9 + tap]   (147456 elements)
__global__ void kTransWf(const float* __restrict__ wf, float* __restrict__ wfT) {
    int tid = blockIdx.x * blockDim.x + threadIdx.x;
    int k = tid & 127;
    int r = tid >> 7;        // 0..1151  (= c*9+tap)
    wfT[tid] = wf[(size_t)k * 1152 + r];
}

// ---------------------------------------------------------------------------
// h[b][o][t] = relu(brd[o] + sum_{c,tap} wrd[o][c][tap] * x[b][c][t+tap-1])
__global__ void kConv1d(const float* __restrict__ x, const float* __restrict__ wrd,
                        const float* __restrict__ brd, float* __restrict__ h) {
    __shared__ float wl[CIN * 3];
    int b = blockIdx.x >> 7;
    int o = blockIdx.x & 127;
    for (int i = threadIdx.x; i < CIN * 3; i += blockDim.x)
        wl[i] = wrd[o * CIN * 3 + i];
    __syncthreads();
    int t = threadIdx.x;
    if (t >= T) return;
    float acc = brd[o];
    const float* xb = x + (size_t)b * CIN * T;
    for (int c = 0; c < CIN; ++c) {
        float xm = (t > 0)     ? xb[c * T + t - 1] : 0.f;
        float x0 =               xb[c * T + t];
        float xp = (t < T - 1) ? xb[c * T + t + 1] : 0.f;
        acc = fmaf(wl[c * 3 + 0], xm, acc);
        acc = fmaf(wl[c * 3 + 1], x0, acc);
        acc = fmaf(wl[c * 3 + 2], xp, acc);
    }
    h[((size_t)b * C1 + o) * T + t] = fmaxf(acc, 0.f);
}

// ---------------------------------------------------------------------------
// Q[b][s][t][o] = sum_c w3dT[s][c][o] * h[b][c][t]
__global__ __launch_bounds__(512, 4)
void kQ(const float* __restrict__ w3dT, const float* __restrict__ h,
        float* __restrict__ Q) {
    int blk = blockIdx.x;            // 4*32*4 = 512 blocks
    int tc = blk & 3;
    int s  = (blk >> 2) & 31;
    int b  = blk >> 7;
    int o  = threadIdx.x;            // 512
    int t0 = tc * 25;
    float acc[25];
#pragma unroll
    for (int j = 0; j < 25; ++j) acc[j] = 0.f;
    const float* wp = w3dT + (size_t)s * 128 * 512 + o;
    const float* hp = h + (size_t)b * C1 * T + t0;
    for (int c = 0; c < C1; ++c) {
        float w = wp[(size_t)c * 512];
#pragma unroll
        for (int j = 0; j < 25; ++j)
            acc[j] = fmaf(w, hp[c * T + j], acc[j]);   // hp uniform -> scalar loads
    }
    float* qp = Q + (((size_t)b * S + s) * T + t0) * 512 + o;
#pragma unroll
    for (int j = 0; j < 25; ++j) qp[(size_t)j * 512] = acc[j];
}

// ---------------------------------------------------------------------------
// m3[b][du][o] = relu(b3d[o] + sum_{s,t} mask[t][s][d][u] * Q[b][s][t][o])
__global__ __launch_bounds__(512, 2)
void kM3(const float* __restrict__ Q, const float* __restrict__ mask,
         const float* __restrict__ b3d, float* __restrict__ m3) {
    int blk = blockIdx.x;            // 4*100*7 = 2800
    int ut = blk % 7;
    int d  = (blk / 7) % 100;
    int b  = blk / 700;
    int o  = threadIdx.x;            // 512
    int u0 = ut * 16;
    float bias = b3d[o];
    float acc[16];
#pragma unroll
    for (int i = 0; i < 16; ++i) acc[i] = bias;

    double step = (2.0 * d + 1.0) / 95.0;      // plen/(num_sample*perbin-1)
    double xoff = -0.5 * (d + 1.0);            // -ratio*clen
    const float* Qb = Q + (size_t)b * S * T * 512 + o;
    bool full = (u0 + 16 <= 100);

    for (int s = 0; s < S; ++s) {
        double pmin = (double)u0 + xoff + step * (3 * s);
        double pmax = (double)(u0 + 15) + xoff + step * (3 * s + 2);
        int t0 = (int)floor(pmin) - 1; if (t0 < 0)  t0 = 0;
        int t1 = (int)ceil(pmax) + 1;  if (t1 > 99) t1 = 99;
        const float* Qs = Qb + (size_t)s * T * 512;
        for (int t = t0; t <= t1; ++t) {
            float qv = Qs[(size_t)t * 512];
            const float* mrow = mask + (((size_t)t * S + s) * D + d) * T + u0;
            if (full) {
#pragma unroll
                for (int uu = 0; uu < 16; ++uu)
                    acc[uu] = fmaf(mrow[uu], qv, acc[uu]);
            } else {
#pragma unroll
                for (int uu = 0; uu < 16; ++uu)
                    if (u0 + uu < 100)
                        acc[uu] = fmaf(mrow[uu], qv, acc[uu]);
            }
        }
    }
#pragma unroll
    for (int uu = 0; uu < 16; ++uu) {
        int u = u0 + uu;
        if (u < 100)
            m3[((size_t)b * DU + d * 100 + u) * 512 + o] = fmaxf(acc[uu], 0.f);
    }
}

// ---------------------------------------------------------------------------
// m2[b][du][k] = relu(b2d[k] + sum_o m3[b][du][o] * w2d[k][o])
// Register-tiled GEMM: block = 64 du x 128 k, thread = 4 du x 8 k.
// No local arrays except literal-indexed acc (scratch-SROA hazard).
#define KM2_FMA8(I, A) \
    acc[I][0] = fmaf((A), c0.x, acc[I][0]); \
    acc[I][1] = fmaf((A), c0.y, acc[I][1]); \
    acc[I][2] = fmaf((A), c0.z, acc[I][2]); \
    acc[I][3] = fmaf((A), c0.w, acc[I][3]); \
    acc[I][4] = fmaf((A), c1.x, acc[I][4]); \
    acc[I][5] = fmaf((A), c1.y, acc[I][5]); \
    acc[I][6] = fmaf((A), c1.z, acc[I][6]); \
    acc[I][7] = fmaf((A), c1.w, acc[I][7]);

__global__ __launch_bounds__(256, 2)
void kM2(const float* __restrict__ m3, const float* __restrict__ w2dT,
         const float* __restrict__ b2d, float* __restrict__ m2) {
    __shared__ float mA[64][65];       // [du_local][o_local], padded
    __shared__ float wB[64 * 128];     // [o_local][k]
    int blk  = blockIdx.x;             // 4 * 157
    int tile = blk % 157;
    int b    = blk / 157;
    int du0  = tile * 64;
    int tid  = threadIdx.x;
    int tk   = tid & 15;
    int tdu  = tid >> 4;
    float acc[4][8];
#pragma unroll
    for (int i = 0; i < 4; ++i)
#pragma unroll
        for (int j = 0; j < 8; ++j) acc[i][j] = 0.f;

    for (int oc = 0; oc < 8; ++oc) {
        __syncthreads();
        for (int it = 0; it < 16; ++it) {
            int idx = it * 256 + tid;              // 4096
            int j = idx >> 6, op = idx & 63;
            int du = du0 + j;
            mA[j][op] = (du < DU) ? m3[((size_t)b * DU + du) * 512 + oc * 64 + op] : 0.f;
        }
        for (int it = 0; it < 32; ++it) {
            int idx = it * 256 + tid;              // 8192
            wB[idx] = w2dT[(size_t)(oc * 64 + (idx >> 7)) * 128 + (idx & 127)];
        }
        __syncthreads();
        for (int op = 0; op < 64; ++op) {
            float a0 = mA[tdu * 4 + 0][op];
            float a1 = mA[tdu * 4 + 1][op];
            float a2 = mA[tdu * 4 + 2][op];
            float a3 = mA[tdu * 4 + 3][op];
            float4 c0 = *(const float4*)&wB[op * 128 + tk * 8];
            float4 c1 = *(const float4*)&wB[op * 128 + tk * 8 + 4];
            KM2_FMA8(0, a0)
            KM2_FMA8(1, a1)
            KM2_FMA8(2, a2)
            KM2_FMA8(3, a3)
        }
    }
#pragma unroll
    for (int i = 0; i < 4; ++i) {
        int du = du0 + tdu * 4 + i;
        if (du < DU) {
#pragma unroll
            for (int j = 0; j < 8; ++j) {
                int k = tk * 8 + j;
                m2[((size_t)b * DU + du) * 128 + k] = fmaxf(acc[i][j] + b2d[k], 0.f);
            }
        }
    }
}

// ---------------------------------------------------------------------------
// 3x3 conv, 128->128, channels-last [b][d][u][c].
// Block = (b, d, k-half): 100 u x 64 k. 256 threads = 8 kg(x8k) x 32 uu
// (active uu<25, u = j*25+uu, j=0..3 -> NO guard in hot loop).
// LDS: weights chunk 72x64 (18.4 KB) + input rows pitch-9 (11.9 KB) = 30 KB.
// No local arrays except literal-indexed acc.
#define CONV_FMA8(J, A) \
    acc[J][0] = fmaf((A), wA.x, acc[J][0]); \
    acc[J][1] = fmaf((A), wA.y, acc[J][1]); \
    acc[J][2] = fmaf((A), wA.z, acc[J][2]); \
    acc[J][3] = fmaf((A), wA.w, acc[J][3]); \
    acc[J][4] = fmaf((A), wC.x, acc[J][4]); \
    acc[J][5] = fmaf((A), wC.y, acc[J][5]); \
    acc[J][6] = fmaf((A), wC.z, acc[J][6]); \
    acc[J][7] = fmaf((A), wC.w, acc[J][7]);

__global__ __launch_bounds__(256, 2)
void kConv3x3(const float* __restrict__ fin, const float* __restrict__ wfT,
              const float* __restrict__ bf, float* __restrict__ fout) {
    __shared__ float wl[72 * 64];          // 18.4 KB
    __shared__ float inl[3 * 110 * 9];     // 11.9 KB (u padded to 110, pitch 9)
    int blk = blockIdx.x;                  // B*D*2 = 800
    int b   = blk / 200;
    int rem = blk % 200;
    int d   = rem >> 1;
    int kh  = rem & 1;
    int tid = threadIdx.x;
    int kg  = tid >> 5;                    // 0..7  -> 8 output channels each
    int uu  = tid & 31;                    // 0..31 (active < 25)
    float acc[4][8];
#pragma unroll
    for (int j = 0; j < 4; ++j)
#pragma unroll
        for (int kk = 0; kk < 8; ++kk) acc[j][kk] = 0.f;

    for (int cc = 0; cc < 16; ++cc) {      // 16 chunks of 8 input channels
        __syncthreads();
        // stage weights: wl[row*64+kk] = wfT[(cc*72+row)*128 + kh*64 + kk]
        for (int i = tid; i < 4608; i += 256)
            wl[i] = wfT[(size_t)(cc * 72 + (i >> 6)) * 128 + kh * 64 + (i & 63)];
        // stage input halo: inl[(dy*110+up)*9+c] = fin[b][d-1+dy][up-1][cc*8+c]
        for (int i = tid; i < 2448; i += 256) {
            int c  = i & 7;
            int up = (i >> 3) % 102;
            int dy = (i >> 3) / 102;
            int dr = d - 1 + dy;
            int su = up - 1;
            float v = 0.f;
            if (dr >= 0 && dr < 100 && su >= 0 && su < 100)
                v = fin[((size_t)b * DU + dr * 100 + su) * 128 + cc * 8 + c];
            inl[(dy * 110 + up) * 9 + c] = v;
        }
        __syncthreads();
#pragma unroll
        for (int c = 0; c < 8; ++c) {
#pragma unroll
            for (int tap = 0; tap < 9; ++tap) {
                const int dy = tap / 3, dx = tap % 3;
                float4 wA = *(const float4*)&wl[(c * 9 + tap) * 64 + kg * 8];
                float4 wC = *(const float4*)&wl[(c * 9 + tap) * 64 + kg * 8 + 4];
                float a0 = inl[(dy * 110 + uu      + dx) * 9 + c];
                float a1 = inl[(dy * 110 + uu + 25 + dx) * 9 + c];
                float a2 = inl[(dy * 110 + uu + 50 + dx) * 9 + c];
                float a3 = inl[(dy * 110 + uu + 75 + dx) * 9 + c];
                CONV_FMA8(0, a0)
                CONV_FMA8(1, a1)
                CONV_FMA8(2, a2)
                CONV_FMA8(3, a3)
            }
        }
    }
    if (uu < 25) {
#pragma unroll
        for (int j = 0; j < 4; ++j) {
            int u = j * 25 + uu;
            size_t base = ((size_t)b * DU + d * 100 + u) * 128 + kh * 64 + kg * 8;
#pragma unroll
            for (int kk = 0; kk < 8; ++kk)
                fout[base + kk] = fmaxf(acc[j][kk] + bf[kh * 64 + kg * 8 + kk], 0.f);
        }
    }
}

// ---------------------------------------------------------------------------
// out[b][k2][d][u] = sigmoid(bf3[k2] + sum_c f2[b][du][c]*wf3[k2][c])
__global__ void kHead(const float* __restrict__ f2, const float* __restrict__ wf3,
                      const float* __restrict__ bf3, float* __restrict__ out) {
    int gid = blockIdx.x * blockDim.x + threadIdx.x;
    if (gid >= B * DU) return;
    int b  = gid / DU;
    int du = gid % DU;
    const float* fp = f2 + (size_t)gid * 128;
    float d0 = 0.f, d1 = 0.f;
    for (int c = 0; c < 128; ++c) {
        float v = fp[c];
        d0 = fmaf(v, wf3[c], d0);
        d1 = fmaf(v, wf3[128 + c], d1);
    }
    d0 += bf3[0];
    d1 += bf3[1];
    out[((size_t)b * 2 + 0) * DU + du] = 1.f / (1.f + expf(-d0));
    out[((size_t)b * 2 + 1) * DU + du] = 1.f / (1.f + expf(-d1));
}

// ---------------------------------------------------------------------------
extern "C" void kernel_launch(void* const* d_in, const int* in_sizes, int n_in,
                              void* d_out, int out_size, void* d_ws, size_t ws_size,
                              hipStream_t stream) {
    const float* x    = (const float*)d_in[0];
    const float* wrd  = (const float*)d_in[1];
    const float* brd  = (const float*)d_in[2];
    const float* w3d  = (const float*)d_in[3];
    const float* b3d  = (const float*)d_in[4];
    const float* w2d  = (const float*)d_in[5];
    const float* b2d  = (const float*)d_in[6];
    const float* wf1  = (const float*)d_in[7];
    const float* bf1  = (const float*)d_in[8];
    const float* wf2  = (const float*)d_in[9];
    const float* bf2  = (const float*)d_in[10];
    const float* wf3  = (const float*)d_in[11];
    const float* bf3  = (const float*)d_in[12];
    const float* mask = (const float*)d_in[13];

    float* ws   = (float*)d_ws;
    float* h    = ws;                       // 51,200
    float* w3dT = h    + 51200;             // 2,097,152
    float* w2dT = w3dT + 2097152;           // 65,536
    float* Q    = w2dT + 65536;             // 6,553,600
    float* m3L  = Q    + 6553600;           // 20,480,000
    float* m2L  = m3L  + 20480000;          // 5,120,000
    float* f1   = m3L;                      // alias: m3 dead after kM2
    float* f2   = m3L + 5120000;            // alias
    float* wfT1 = m3L + 10240000;           // alias tail of m3 region (147,456)
    float* wfT2 = wfT1 + 147456;            // 147,456

    kTransW3<<<8192, 256, 0, stream>>>(w3d, w3dT);
    kTransW2<<<256, 256, 0, stream>>>(w2d, w2dT);
    kConv1d<<<B * C1, 128, 0, stream>>>(x, wrd, brd, h);
    kQ<<<B * S * 4, 512, 0, stream>>>(w3dT, h, Q);
    kM3<<<B * D * 7, 512, 0, stream>>>(Q, mask, b3d, m3L);
    kM2<<<B * 157, 256, 0, stream>>>(m3L, w2dT, b2d, m2L);
    // weight transposes for the 3x3 convs (m3 region is dead now -> tail reuse)
    kTransWf<<<576, 256, 0, stream>>>(wf1, wfT1);
    kTransWf<<<576, 256, 0, stream>>>(wf2, wfT2);
    kConv3x3<<<B * D * 2, 256, 0, stream>>>(m2L, wfT1, bf1, f1);
    kConv3x3<<<B * D * 2, 256, 0, stream>>>(f1, wfT2, bf2, f2);
    kHead<<<(B * DU + 255) / 256, 256, 0, stream>>>(f2, wf3, bf3, (float*)d_out);
}

// Round 5
// 583.654 us; speedup vs baseline: 20.3528x; 2.5610x over previous
//
#include <hip/hip_runtime.h>
#include <hip/hip_bf16.h>
#include <cstdint>
#include <cstddef>

// Problem constants (match reference)
static constexpr int B   = 4;
static constexpr int CIN = 256;
static constexpr int T   = 100;   // time / start dim
static constexpr int D   = 100;   // duration dim
static constexpr int S   = 32;    // num_sample bins
static constexpr int C1  = 128;   // reduced channels
static constexpr int DU  = D * T; // 10000

typedef __attribute__((ext_vector_type(8))) short bfv8;   // 8 bf16 (4 VGPR)
typedef __attribute__((ext_vector_type(4))) float fx4;    // MFMA accumulator

static __device__ __forceinline__ unsigned short f2bf(float f) {
    unsigned int x = __float_as_uint(f);
    x += 0x7FFFu + ((x >> 16) & 1u);           // RNE to bf16
    return (unsigned short)(x >> 16);
}
static __device__ __forceinline__ unsigned int pk2(float a, float b) {
    return (unsigned int)f2bf(a) | ((unsigned int)f2bf(b) << 16);
}

// ---------------------------------------------------------------------------
// w3dT[s][c][o] = w3d[o][c][s]
__global__ void kTransW3(const float* __restrict__ w3d, float* __restrict__ w3dT) {
    int tid = blockIdx.x * blockDim.x + threadIdx.x;   // 2,097,152
    int o = tid & 511;
    int c = (tid >> 9) & 127;
    int s = tid >> 16;
    w3dT[tid] = w3d[(o * 128 + c) * 32 + s];
}

// w2b[k][o] = bf16(w2d[k][o])  (layout unchanged, just cvt)
__global__ void kTransW2B(const float* __restrict__ w2d, unsigned short* __restrict__ w2b) {
    int tid = blockIdx.x * blockDim.x + threadIdx.x;   // 65536
    w2b[tid] = f2bf(w2d[tid]);
}

// wfb[tap][k][c] = bf16(wf[k][c][tap])   (9*128*128)
__global__ void kTransWfB(const float* __restrict__ wf, unsigned short* __restrict__ wfb) {
    int tid = blockIdx.x * blockDim.x + threadIdx.x;   // 147456
    int c   = tid & 127;
    int k   = (tid >> 7) & 127;
    int tap = tid >> 14;
    wfb[tid] = f2bf(wf[(size_t)(k * 128 + c) * 9 + tap]);
}

// ---------------------------------------------------------------------------
// h[b][o][t] = relu(brd[o] + sum_{c,tap} wrd[o][c][tap] * x[b][c][t+tap-1])
__global__ void kConv1d(const float* __restrict__ x, const float* __restrict__ wrd,
                        const float* __restrict__ brd, float* __restrict__ h) {
    __shared__ float wl[CIN * 3];
    int b = blockIdx.x >> 7;
    int o = blockIdx.x & 127;
    for (int i = threadIdx.x; i < CIN * 3; i += blockDim.x)
        wl[i] = wrd[o * CIN * 3 + i];
    __syncthreads();
    int t = threadIdx.x;
    if (t >= T) return;
    float acc = brd[o];
    const float* xb = x + (size_t)b * CIN * T;
    for (int c = 0; c < CIN; ++c) {
        float xm = (t > 0)     ? xb[c * T + t - 1] : 0.f;
        float x0 =               xb[c * T + t];
        float xp = (t < T - 1) ? xb[c * T + t + 1] : 0.f;
        acc = fmaf(wl[c * 3 + 0], xm, acc);
        acc = fmaf(wl[c * 3 + 1], x0, acc);
        acc = fmaf(wl[c * 3 + 2], xp, acc);
    }
    h[((size_t)b * C1 + o) * T + t] = fmaxf(acc, 0.f);
}

// ---------------------------------------------------------------------------
// Q[b][s][t][o] = sum_c w3dT[s][c][o] * h[b][c][t]   (fp32)
__global__ __launch_bounds__(512, 4)
void kQ(const float* __restrict__ w3dT, const float* __restrict__ h,
        float* __restrict__ Q) {
    int blk = blockIdx.x;            // 4*32*4 = 512 blocks
    int tc = blk & 3;
    int s  = (blk >> 2) & 31;
    int b  = blk >> 7;
    int o  = threadIdx.x;            // 512
    int t0 = tc * 25;
    float acc[25];
#pragma unroll
    for (int j = 0; j < 25; ++j) acc[j] = 0.f;
    const float* wp = w3dT + (size_t)s * 128 * 512 + o;
    const float* hp = h + (size_t)b * C1 * T + t0;
    for (int c = 0; c < C1; ++c) {
        float w = wp[(size_t)c * 512];
#pragma unroll
        for (int j = 0; j < 25; ++j)
            acc[j] = fmaf(w, hp[c * T + j], acc[j]);
    }
    float* qp = Q + (((size_t)b * S + s) * T + t0) * 512 + o;
#pragma unroll
    for (int j = 0; j < 25; ++j) qp[(size_t)j * 512] = acc[j];
}

// ---------------------------------------------------------------------------
// QT[b][s][o][t(128)] = bf16(Q[b][s][t][o]); t in [100,128) zero-padded.
__global__ __launch_bounds__(256, 4)
void kQT(const float* __restrict__ Q, unsigned int* __restrict__ QT) {
    __shared__ float lds[100][65];
    int blk = blockIdx.x;            // b*256 + s*8 + oc  = 1024
    int oc = blk & 7;
    int s  = (blk >> 3) & 31;
    int b  = blk >> 8;
    int tid = threadIdx.x;
    const float* qp = Q + ((size_t)(b * 32 + s) * 100) * 512 + oc * 64;
    for (int i = tid; i < 6400; i += 256) {
        int t = i >> 6, o = i & 63;
        lds[t][o] = qp[(size_t)t * 512 + o];
    }
    __syncthreads();
    unsigned int* outp = QT + ((size_t)(b * 32 + s) * 512 + oc * 64) * 64;
    for (int i = tid; i < 4096; i += 256) {
        int orow = i >> 6, col = i & 63;
        int t0 = col * 2;
        unsigned int v = 0;
        if (t0 < 100) v = pk2(lds[t0][orow], lds[t0 + 1][orow]);
        outp[(size_t)orow * 64 + col] = v;
    }
}

// ---------------------------------------------------------------------------
// m3b[b][du][o] = bf16(relu(b3d[o] + sum_{s,t} mask[t][s][d][u]*Q[b][s][t][o]))
// MFMA: per s exactly one K=32 window of t (support width <= 23.3 < 32).
// A = mask (u x t) gathered from global fp32; B = QT bf16 rows (zero-padded).
__global__ __launch_bounds__(256, 4)
void kM3m(const float* __restrict__ mask, const unsigned short* __restrict__ QT,
          const float* __restrict__ b3d, unsigned short* __restrict__ m3b) {
    int blk = blockIdx.x;            // b*700 + d*7 + ut  = 2800
    int ut = blk % 7;
    int d  = (blk / 7) % 100;
    int b  = blk / 700;
    int u0 = ut * 16;
    int tid = threadIdx.x;
    int w   = tid >> 6;              // wave 0..3 -> o range w*128
    int l   = tid & 63;
    int l15 = l & 15, lg = l >> 4;
    fx4 acc[8];
#pragma unroll
    for (int n = 0; n < 8; ++n) acc[n] = (fx4){0.f, 0.f, 0.f, 0.f};

    float step = (2.f * d + 1.f) * (1.f / 95.f);
    float xoff = -0.5f * (d + 1.f);
    int um = u0 + l15; if (um > 99) um = 99;           // clamped rows discarded

    for (int s = 0; s < 32; ++s) {
        float pmin = (float)u0 + xoff + step * (3 * s);
        float pmax = pmin + 15.f + 2.f * step;
        if (pmin > 100.01f || pmax < -1.01f) continue;
        int t0 = (int)floorf(pmin) - 1;
        if (t0 < 0) t0 = 0;
        t0 &= ~7;
        if (t0 > 96) t0 = 96;
        int tb = t0 + lg * 8;
        const float* mp = mask + ((size_t)s * 100 + d) * 100 + um;
        bfv8 a;
#pragma unroll
        for (int j = 0; j < 8; ++j) {
            int t = tb + j; if (t > 99) t = 99;        // B is zero there anyway
            a[j] = (short)f2bf(mp[(size_t)t * 320000]);
        }
        const unsigned short* qs = QT + ((size_t)(b * 32 + s) * 512 + w * 128 + l15) * 128
                                      + t0 + lg * 8;
#pragma unroll
        for (int n = 0; n < 8; ++n) {
            bfv8 bq = *(const bfv8*)(qs + (size_t)n * 16 * 128);
            acc[n] = __builtin_amdgcn_mfma_f32_16x16x32_bf16(a, bq, acc[n], 0, 0, 0);
        }
    }
#pragma unroll
    for (int n = 0; n < 8; ++n) {
        int o = w * 128 + n * 16 + l15;
        float bias = b3d[o];
#pragma unroll
        for (int r = 0; r < 4; ++r) {
            int u = u0 + lg * 4 + r;
            if (u < 100)
                m3b[((size_t)b * DU + d * 100 + u) * 512 + o] =
                    f2bf(fmaxf(acc[n][r] + bias, 0.f));
        }
    }
}

// ---------------------------------------------------------------------------
// m2[b][du][k] = relu(b2d[k] + sum_o m3b[b][du][o]*w2b[k][o])  -- MFMA GEMM
__global__ __launch_bounds__(256, 4)
void kM2m(const unsigned short* __restrict__ m3b, const unsigned short* __restrict__ w2b,
          const float* __restrict__ b2d, float* __restrict__ m2) {
    int blk  = blockIdx.x;           // 4 * 157
    int tile = blk % 157;
    int b    = blk / 157;
    int du0  = tile * 64;
    int tid = threadIdx.x;
    int w   = tid >> 6;              // wave -> du sub-tile of 16
    int l   = tid & 63;
    int l15 = l & 15, lg = l >> 4;
    fx4 acc[8];
#pragma unroll
    for (int n = 0; n < 8; ++n) acc[n] = (fx4){0.f, 0.f, 0.f, 0.f};

    int dua = du0 + w * 16 + l15; if (dua > 9999) dua = 9999;   // ragged clamp
    const unsigned short* ap = m3b + ((size_t)b * DU + dua) * 512;
#pragma unroll 4
    for (int ks = 0; ks < 16; ++ks) {
        bfv8 a = *(const bfv8*)(ap + ks * 32 + lg * 8);
#pragma unroll
        for (int n = 0; n < 8; ++n) {
            bfv8 bq = *(const bfv8*)(w2b + (size_t)(n * 16 + l15) * 512 + ks * 32 + lg * 8);
            acc[n] = __builtin_amdgcn_mfma_f32_16x16x32_bf16(a, bq, acc[n], 0, 0, 0);
        }
    }
#pragma unroll
    for (int n = 0; n < 8; ++n) {
        int k = n * 16 + l15;
        float bias = b2d[k];
#pragma unroll
        for (int r = 0; r < 4; ++r) {
            int du = du0 + w * 16 + lg * 4 + r;
            if (du < DU)
                m2[((size_t)b * DU + du) * 128 + k] = fmaxf(acc[n][r] + bias, 0.f);
        }
    }
}

// ---------------------------------------------------------------------------
// 3x3 conv 128->128 via implicit GEMM (tap-outer), bf16 MFMA, fp32 accum.
// Block: (b, d-tile of 4, u-tile of 16); wave w -> d = d0+w; out 16u x 128k.
__global__ __launch_bounds__(256, 2)
void kConvM(const float* __restrict__ fin, const unsigned short* __restrict__ wfb,
            const float* __restrict__ bf, float* __restrict__ fout) {
    __shared__ unsigned short slab[6 * 18 * 128];   // 27.6 KB, XOR-swizzled rows
    __shared__ unsigned short wl[128 * 128];        // 32 KB,  XOR-swizzled rows
    int blk = blockIdx.x;            // b*175 + dt*7 + ut = 700
    int ut = blk % 7;
    int dt = (blk / 7) % 25;
    int b  = blk / 175;
    int u0 = ut * 16, d0 = dt * 4;
    int tid = threadIdx.x;
    int w   = tid >> 6;
    int l   = tid & 63;
    int l15 = l & 15, lg = l >> 4;
    fx4 acc[8];
#pragma unroll
    for (int n = 0; n < 8; ++n) acc[n] = (fx4){0.f, 0.f, 0.f, 0.f};

    // stage input slab: rows (dd,uu) = in[b][d0-1+dd][u0-1+uu][c], bf16
    for (int i = tid; i < 1728; i += 256) {         // 16B chunks
        int cc = i & 15;
        int uu = (i >> 4) % 18;
        int dd = (i >> 4) / 18;
        int dr = d0 - 1 + dd, su = u0 - 1 + uu;
        uint4 v = {0u, 0u, 0u, 0u};
        if (dr >= 0 && dr < 100 && su >= 0 && su < 100) {
            const float* p = fin + ((size_t)b * DU + dr * 100 + su) * 128 + cc * 8;
            float4 f0 = *(const float4*)p;
            float4 f1 = *(const float4*)(p + 4);
            v.x = pk2(f0.x, f0.y); v.y = pk2(f0.z, f0.w);
            v.z = pk2(f1.x, f1.y); v.w = pk2(f1.z, f1.w);
        }
        int byte = (dd * 18 + uu) * 256 + ((cc * 16) ^ ((uu & 7) << 4));
        *(uint4*)((char*)slab + byte) = v;
    }

    for (int tap = 0; tap < 9; ++tap) {
        int dy = tap / 3, dx = tap % 3;
        __syncthreads();                             // prior reads of wl done
        for (int i = tid; i < 2048; i += 256) {      // stage W[tap]: 16B chunks
            int k = i >> 4, cc = i & 15;
            uint4 v = *(const uint4*)(wfb + ((size_t)tap * 128 + k) * 128 + cc * 8);
            int byte = k * 256 + ((cc * 16) ^ ((k & 7) << 4));
            *(uint4*)((char*)wl + byte) = v;
        }
        __syncthreads();
        int uu = l15 + dx;
        int ddr = w + dy;
        int arow = (ddr * 18 + uu) * 256;
        int aswz = (uu & 7) << 4;
#pragma unroll
        for (int cs = 0; cs < 4; ++cs) {
            int cbyte = (cs * 32 + lg * 8) * 2;
            bfv8 a = *(const bfv8*)((const char*)slab + arow + (cbyte ^ aswz));
#pragma unroll
            for (int n = 0; n < 8; ++n) {
                int k = n * 16 + l15;
                bfv8 bq = *(const bfv8*)((const char*)wl + k * 256 + (cbyte ^ ((k & 7) << 4)));
                acc[n] = __builtin_amdgcn_mfma_f32_16x16x32_bf16(a, bq, acc[n], 0, 0, 0);
            }
        }
    }
    int d = d0 + w;
#pragma unroll
    for (int n = 0; n < 8; ++n) {
        int k = n * 16 + l15;
        float bias = bf[k];
#pragma unroll
        for (int r = 0; r < 4; ++r) {
            int u = u0 + lg * 4 + r;
            if (u < 100)
                fout[((size_t)b * DU + d * 100 + u) * 128 + k] =
                    fmaxf(acc[n][r] + bias, 0.f);
        }
    }
}

// ---------------------------------------------------------------------------
// out[b][k2][d][u] = sigmoid(bf3[k2] + sum_c f2[b][du][c]*wf3[k2][c])
__global__ void kHead(const float* __restrict__ f2, const float* __restrict__ wf3,
                      const float* __restrict__ bf3, float* __restrict__ out) {
    int gid = blockIdx.x * blockDim.x + threadIdx.x;
    if (gid >= B * DU) return;
    int b  = gid / DU;
    int du = gid % DU;
    const float* fp = f2 + (size_t)gid * 128;
    float d0 = 0.f, d1 = 0.f;
    for (int c = 0; c < 128; ++c) {
        float v = fp[c];
        d0 = fmaf(v, wf3[c], d0);
        d1 = fmaf(v, wf3[128 + c], d1);
    }
    d0 += bf3[0];
    d1 += bf3[1];
    out[((size_t)b * 2 + 0) * DU + du] = 1.f / (1.f + expf(-d0));
    out[((size_t)b * 2 + 1) * DU + du] = 1.f / (1.f + expf(-d1));
}

// ---------------------------------------------------------------------------
extern "C" void kernel_launch(void* const* d_in, const int* in_sizes, int n_in,
                              void* d_out, int out_size, void* d_ws, size_t ws_size,
                              hipStream_t stream) {
    const float* x    = (const float*)d_in[0];
    const float* wrd  = (const float*)d_in[1];
    const float* brd  = (const float*)d_in[2];
    const float* w3d  = (const float*)d_in[3];
    const float* b3d  = (const float*)d_in[4];
    const float* w2d  = (const float*)d_in[5];
    const float* b2d  = (const float*)d_in[6];
    const float* wf1  = (const float*)d_in[7];
    const float* bf1  = (const float*)d_in[8];
    const float* wf2  = (const float*)d_in[9];
    const float* bf2  = (const float*)d_in[10];
    const float* wf3  = (const float*)d_in[11];
    const float* bf3  = (const float*)d_in[12];
    const float* mask = (const float*)d_in[13];

    float* ws = (float*)d_ws;
    // layout (float units):
    float* h     = ws;                              // 51,200
    float* w3dT  = h + 51200;                       // 2,097,152 -> 2,148,352
    unsigned short* w2b  = (unsigned short*)(ws + 2148352);   // 65,536 us (32,768 f)
    unsigned short* wfb1 = (unsigned short*)(ws + 2181120);   // 147,456 us (73,728 f)
    unsigned short* wfb2 = (unsigned short*)(ws + 2254848);   // 147,456 us
    unsigned int*   QT   = (unsigned int*)(ws + 2328576);     // 8,388,608 us (4,194,304 f)
    unsigned short* m3b  = (unsigned short*)(ws + 6522880);   // 20,480,000 us (10,240,000 f)
    float* Qf    = ws + 6522880;                    // fp32 Q aliases m3b (dead before kM3m)
    float* m2L   = ws + 16762880;                   // 5,120,000
    float* f1    = ws + 21882880;                   // 5,120,000
    float* f2    = ws + 27002880;                   // 5,120,000  (end 32,122,880 f = 128.5 MB)

    kTransW3<<<8192, 256, 0, stream>>>(w3d, w3dT);
    kTransW2B<<<256, 256, 0, stream>>>(w2d, w2b);
    kTransWfB<<<576, 256, 0, stream>>>(wf1, wfb1);
    kTransWfB<<<576, 256, 0, stream>>>(wf2, wfb2);
    kConv1d<<<B * C1, 128, 0, stream>>>(x, wrd, brd, h);
    kQ<<<B * S * 4, 512, 0, stream>>>(w3dT, h, Qf);
    kQT<<<1024, 256, 0, stream>>>(Qf, QT);
    kM3m<<<B * D * 7, 256, 0, stream>>>(mask, (const unsigned short*)QT, b3d, m3b);
    kM2m<<<B * 157, 256, 0, stream>>>(m3b, w2b, b2d, m2L);
    kConvM<<<B * 25 * 7, 256, 0, stream>>>(m2L, wfb1, bf1, f1);
    kConvM<<<B * 25 * 7, 256, 0, stream>>>(f1, wfb2, bf2, f2);
    kHead<<<(B * DU + 255) / 256, 256, 0, stream>>>(f2, wf3, bf3, (float*)d_out);
}

// Round 6
// 461.935 us; speedup vs baseline: 25.7158x; 1.2635x over previous
//
#include <hip/hip_runtime.h>
#include <hip/hip_bf16.h>
#include <cstdint>
#include <cstddef>

// Problem constants (match reference)
static constexpr int B   = 4;
static constexpr int CIN = 256;
static constexpr int T   = 100;   // time / start dim
static constexpr int D   = 100;   // duration dim
static constexpr int S   = 32;    // num_sample bins
static constexpr int C1  = 128;   // reduced channels
static constexpr int DU  = D * T; // 10000

typedef __attribute__((ext_vector_type(8))) short bfv8;   // 8 bf16 (4 VGPR)
typedef __attribute__((ext_vector_type(4))) float fx4;    // MFMA accumulator
typedef unsigned short us;

static __device__ __forceinline__ unsigned short f2bf(float f) {
    unsigned int x = __float_as_uint(f);
    x += 0x7FFFu + ((x >> 16) & 1u);           // RNE to bf16
    return (unsigned short)(x >> 16);
}
static __device__ __forceinline__ unsigned int pk2(float a, float b) {
    return (unsigned int)f2bf(a) | ((unsigned int)f2bf(b) << 16);
}

// ---------------------------------------------------------------------------
// w3B[s][o][c] = bf16(w3d[o][c][s])
__global__ void kTransW3B(const float* __restrict__ w3d, us* __restrict__ w3B) {
    int tid = blockIdx.x * blockDim.x + threadIdx.x;   // 2,097,152
    int c = tid & 127;
    int o = (tid >> 7) & 511;
    int s = tid >> 16;
    w3B[tid] = f2bf(w3d[(o * 128 + c) * 32 + s]);
}

// w2b[k][o] = bf16(w2d[k][o])
__global__ void kTransW2B(const float* __restrict__ w2d, us* __restrict__ w2b) {
    int tid = blockIdx.x * blockDim.x + threadIdx.x;   // 65536
    w2b[tid] = f2bf(w2d[tid]);
}

// wfb[tap][k][c] = bf16(wf[k][c][tap])   (9*128*128)
__global__ void kTransWfB(const float* __restrict__ wf, us* __restrict__ wfb) {
    int tid = blockIdx.x * blockDim.x + threadIdx.x;   // 147456
    int c   = tid & 127;
    int k   = (tid >> 7) & 127;
    int tap = tid >> 14;
    wfb[tid] = f2bf(wf[(size_t)(k * 128 + c) * 9 + tap]);
}

// ---------------------------------------------------------------------------
// hT[b][t(128)][c] = bf16(relu(conv1d(x))), t>=100 zero-padded.
__global__ void kConv1d(const float* __restrict__ x, const float* __restrict__ wrd,
                        const float* __restrict__ brd, us* __restrict__ hT) {
    __shared__ float wl[CIN * 3];
    int b = blockIdx.x >> 7;
    int o = blockIdx.x & 127;
    for (int i = threadIdx.x; i < CIN * 3; i += blockDim.x)
        wl[i] = wrd[o * CIN * 3 + i];
    __syncthreads();
    int t = threadIdx.x;          // 0..127
    float val = 0.f;
    if (t < T) {
        float acc = brd[o];
        const float* xb = x + (size_t)b * CIN * T;
        for (int c = 0; c < CIN; ++c) {
            float xm = (t > 0)     ? xb[c * T + t - 1] : 0.f;
            float x0 =               xb[c * T + t];
            float xp = (t < T - 1) ? xb[c * T + t + 1] : 0.f;
            acc = fmaf(wl[c * 3 + 0], xm, acc);
            acc = fmaf(wl[c * 3 + 1], x0, acc);
            acc = fmaf(wl[c * 3 + 2], xp, acc);
        }
        val = fmaxf(acc, 0.f);
    }
    hT[((size_t)b * 128 + t) * 128 + o] = f2bf(val);
}

// ---------------------------------------------------------------------------
// QT[b][s][o][t(128)] = bf16(sum_c w3B[s][o][c] * hT[b][t][c])  -- MFMA GEMM
// Block = (b, s, o-half 256). 4 waves, each 64 o x 128 t; acc 4m x 8n.
__global__ __launch_bounds__(256, 2)
void kQm(const us* __restrict__ w3B, const us* __restrict__ hT,
         us* __restrict__ QT) {
    int bid = blockIdx.x;            // 4*32*2 = 256
    int oh = bid & 1;
    int s  = (bid >> 1) & 31;
    int b  = bid >> 6;
    int tid = threadIdx.x;
    int w   = tid >> 6;
    int l   = tid & 63;
    int l15 = l & 15, lg = l >> 4;
    int obase = oh * 256 + w * 64;
    fx4 acc[4][8];
#pragma unroll
    for (int m = 0; m < 4; ++m)
#pragma unroll
        for (int n = 0; n < 8; ++n) acc[m][n] = (fx4){0.f, 0.f, 0.f, 0.f};

#pragma unroll
    for (int ks = 0; ks < 4; ++ks) {
        int kofs = ks * 32 + lg * 8;
        bfv8 a0 = *(const bfv8*)(w3B + (size_t)(s * 512 + obase + 0 * 16 + l15) * 128 + kofs);
        bfv8 a1 = *(const bfv8*)(w3B + (size_t)(s * 512 + obase + 1 * 16 + l15) * 128 + kofs);
        bfv8 a2 = *(const bfv8*)(w3B + (size_t)(s * 512 + obase + 2 * 16 + l15) * 128 + kofs);
        bfv8 a3 = *(const bfv8*)(w3B + (size_t)(s * 512 + obase + 3 * 16 + l15) * 128 + kofs);
#pragma unroll
        for (int n = 0; n < 8; ++n) {
            bfv8 bq = *(const bfv8*)(hT + (size_t)(b * 128 + n * 16 + l15) * 128 + kofs);
            acc[0][n] = __builtin_amdgcn_mfma_f32_16x16x32_bf16(a0, bq, acc[0][n], 0, 0, 0);
            acc[1][n] = __builtin_amdgcn_mfma_f32_16x16x32_bf16(a1, bq, acc[1][n], 0, 0, 0);
            acc[2][n] = __builtin_amdgcn_mfma_f32_16x16x32_bf16(a2, bq, acc[2][n], 0, 0, 0);
            acc[3][n] = __builtin_amdgcn_mfma_f32_16x16x32_bf16(a3, bq, acc[3][n], 0, 0, 0);
        }
    }
    us* outb = QT + (size_t)(b * 32 + s) * 512 * 128;
#pragma unroll
    for (int m = 0; m < 4; ++m)
#pragma unroll
        for (int n = 0; n < 8; ++n)
#pragma unroll
            for (int r = 0; r < 4; ++r) {
                int o = obase + m * 16 + lg * 4 + r;
                outb[(size_t)o * 128 + n * 16 + l15] = f2bf(acc[m][n][r]);
            }
}

// ---------------------------------------------------------------------------
// maskW pre-pass: gather bf16 A-fragments once.
// maskW[(s*50+dp)*7+ut][di][l][j] = mask[t0+lg*8+j][s][dp*2+di][ut*16+l15]
// t0 is the shared 8-aligned window start for the d-PAIR (width proof: <=31).
__global__ __launch_bounds__(128, 4)
void kMaskW(const float* __restrict__ mask, us* __restrict__ maskW) {
    int bid = blockIdx.x;            // (s*50+dp)*7+ut = 11200
    int ut = bid % 7;
    int dp = (bid / 7) % 50;
    int s  = bid / 350;
    int tid = threadIdx.x;           // 128: di*64 + l
    int di = tid >> 6;
    int l  = tid & 63;
    int l15 = l & 15, lg = l >> 4;
    int u0 = ut * 16;
    int d0 = dp * 2;

    float step0 = (2.f * d0 + 1.f) * (1.f / 95.f);
    float step1 = (2.f * d0 + 3.f) * (1.f / 95.f);
    float xoff0 = -0.5f * (d0 + 1.f);
    float xoff1 = -0.5f * (d0 + 2.f);
    float fs = (float)(3 * s);
    float f0 = xoff0 + fs * step0;
    float f1 = xoff1 + fs * step1;
    float pminT = (float)u0 + fminf(f0, f1);
    float pmaxT = (float)(u0 + 15) + fmaxf(f0 + 2.f * step0, f1 + 2.f * step1);
    bool skip = (pminT > 100.01f) || (pmaxT < -1.01f);
    int t0 = (int)floorf(pminT) - 1;
    if (t0 < 0) t0 = 0;
    t0 &= ~7;
    if (t0 > 96) t0 = 96;

    int u = u0 + l15;
    int d = d0 + di;
    float v[8];
#pragma unroll
    for (int j = 0; j < 8; ++j) {
        int t = t0 + lg * 8 + j;
        v[j] = 0.f;
        if (!skip && t < 100 && u < 100)
            v[j] = mask[(((size_t)t * 32 + s) * 100 + d) * 100 + u];
    }
    uint4 pk;
    pk.x = pk2(v[0], v[1]); pk.y = pk2(v[2], v[3]);
    pk.z = pk2(v[4], v[5]); pk.w = pk2(v[6], v[7]);
    *(uint4*)(maskW + (size_t)bid * 1024 + tid * 8) = pk;
}

// ---------------------------------------------------------------------------
// m3b[b][du][o] = bf16(relu(b3d[o] + sum_{s,t} mask*Q))  -- MFMA, d-pair fused
// Block = (b, d-pair, u-tile16); 4 waves split o (128 each); acc 2d x 8n.
__global__ __launch_bounds__(256, 2)
void kM3m(const us* __restrict__ maskW, const us* __restrict__ QT,
          const float* __restrict__ b3d, us* __restrict__ m3b) {
    int bid = blockIdx.x;            // 1400
    int swz = (bid & 7) * 175 + (bid >> 3);     // chunked XCD swizzle (1400%8==0)
    int b  = swz / 350;
    int r  = swz % 350;
    int dp = r / 7;
    int ut = r % 7;
    int u0 = ut * 16;
    int d0 = dp * 2;
    int tid = threadIdx.x;
    int w   = tid >> 6;
    int l   = tid & 63;
    int l15 = l & 15, lg = l >> 4;
    fx4 acc0[8], acc1[8];
#pragma unroll
    for (int n = 0; n < 8; ++n) {
        acc0[n] = (fx4){0.f, 0.f, 0.f, 0.f};
        acc1[n] = (fx4){0.f, 0.f, 0.f, 0.f};
    }

    float step0 = (2.f * d0 + 1.f) * (1.f / 95.f);
    float step1 = (2.f * d0 + 3.f) * (1.f / 95.f);
    float xoff0 = -0.5f * (d0 + 1.f);
    float xoff1 = -0.5f * (d0 + 2.f);
    const us* QTb = QT + (size_t)b * 32 * 512 * 128 + (size_t)w * 128 * 128
                       + (size_t)l15 * 128 + lg * 8;

    for (int s = 0; s < 32; ++s) {
        float fs = (float)(3 * s);
        float f0 = xoff0 + fs * step0;
        float f1 = xoff1 + fs * step1;
        float pminT = (float)u0 + fminf(f0, f1);
        float pmaxT = (float)(u0 + 15) + fmaxf(f0 + 2.f * step0, f1 + 2.f * step1);
        if (pminT > 100.01f || pmaxT < -1.01f) continue;
        int t0 = (int)floorf(pminT) - 1;
        if (t0 < 0) t0 = 0;
        t0 &= ~7;
        if (t0 > 96) t0 = 96;

        const us* mw = maskW + (size_t)((s * 50 + dp) * 7 + ut) * 1024 + l * 8;
        bfv8 a0 = *(const bfv8*)mw;
        bfv8 a1 = *(const bfv8*)(mw + 512);
        const us* qs = QTb + (size_t)s * 512 * 128 + t0;
#pragma unroll
        for (int n = 0; n < 8; ++n) {
            bfv8 bq = *(const bfv8*)(qs + (size_t)n * 16 * 128);
            acc0[n] = __builtin_amdgcn_mfma_f32_16x16x32_bf16(a0, bq, acc0[n], 0, 0, 0);
            acc1[n] = __builtin_amdgcn_mfma_f32_16x16x32_bf16(a1, bq, acc1[n], 0, 0, 0);
        }
    }
#pragma unroll
    for (int n = 0; n < 8; ++n) {
        int o = w * 128 + n * 16 + l15;
        float bias = b3d[o];
#pragma unroll
        for (int r4 = 0; r4 < 4; ++r4) {
            int u = u0 + lg * 4 + r4;
            if (u < 100) {
                m3b[((size_t)b * DU + d0 * 100 + u) * 512 + o] =
                    f2bf(fmaxf(acc0[n][r4] + bias, 0.f));
                m3b[((size_t)b * DU + (d0 + 1) * 100 + u) * 512 + o] =
                    f2bf(fmaxf(acc1[n][r4] + bias, 0.f));
            }
        }
    }
}

// ---------------------------------------------------------------------------
// m2[b][du][k] = relu(b2d[k] + sum_o m3b[b][du][o]*w2b[k][o])  -- MFMA GEMM
__global__ __launch_bounds__(256, 4)
void kM2m(const us* __restrict__ m3b, const us* __restrict__ w2b,
          const float* __restrict__ b2d, float* __restrict__ m2) {
    int blk  = blockIdx.x;           // 4 * 157
    int tile = blk % 157;
    int b    = blk / 157;
    int du0  = tile * 64;
    int tid = threadIdx.x;
    int w   = tid >> 6;              // wave -> du sub-tile of 16
    int l   = tid & 63;
    int l15 = l & 15, lg = l >> 4;
    fx4 acc[8];
#pragma unroll
    for (int n = 0; n < 8; ++n) acc[n] = (fx4){0.f, 0.f, 0.f, 0.f};

    int dua = du0 + w * 16 + l15; if (dua > 9999) dua = 9999;   // ragged clamp
    const us* ap = m3b + ((size_t)b * DU + dua) * 512;
#pragma unroll 4
    for (int ks = 0; ks < 16; ++ks) {
        bfv8 a = *(const bfv8*)(ap + ks * 32 + lg * 8);
#pragma unroll
        for (int n = 0; n < 8; ++n) {
            bfv8 bq = *(const bfv8*)(w2b + (size_t)(n * 16 + l15) * 512 + ks * 32 + lg * 8);
            acc[n] = __builtin_amdgcn_mfma_f32_16x16x32_bf16(a, bq, acc[n], 0, 0, 0);
        }
    }
#pragma unroll
    for (int n = 0; n < 8; ++n) {
        int k = n * 16 + l15;
        float bias = b2d[k];
#pragma unroll
        for (int r = 0; r < 4; ++r) {
            int du = du0 + w * 16 + lg * 4 + r;
            if (du < DU)
                m2[((size_t)b * DU + du) * 128 + k] = fmaxf(acc[n][r] + bias, 0.f);
        }
    }
}

// ---------------------------------------------------------------------------
// 3x3 conv 128->128 via implicit GEMM (tap-outer), bf16 MFMA, fp32 accum.
// Block: (b, d-tile of 4, u-tile of 16); wave w -> d = d0+w; out 16u x 128k.
__global__ __launch_bounds__(256, 2)
void kConvM(const float* __restrict__ fin, const us* __restrict__ wfb,
            const float* __restrict__ bf, float* __restrict__ fout) {
    __shared__ us slab[6 * 18 * 128];   // 27.6 KB, XOR-swizzled rows
    __shared__ us wl[128 * 128];        // 32 KB,  XOR-swizzled rows
    int blk = blockIdx.x;            // b*175 + dt*7 + ut = 700
    int ut = blk % 7;
    int dt = (blk / 7) % 25;
    int b  = blk / 175;
    int u0 = ut * 16, d0 = dt * 4;
    int tid = threadIdx.x;
    int w   = tid >> 6;
    int l   = tid & 63;
    int l15 = l & 15, lg = l >> 4;
    fx4 acc[8];
#pragma unroll
    for (int n = 0; n < 8; ++n) acc[n] = (fx4){0.f, 0.f, 0.f, 0.f};

    // stage input slab: rows (dd,uu) = in[b][d0-1+dd][u0-1+uu][c], bf16
    for (int i = tid; i < 1728; i += 256) {         // 16B chunks
        int cc = i & 15;
        int uu = (i >> 4) % 18;
        int dd = (i >> 4) / 18;
        int dr = d0 - 1 + dd, su = u0 - 1 + uu;
        uint4 v = {0u, 0u, 0u, 0u};
        if (dr >= 0 && dr < 100 && su >= 0 && su < 100) {
            const float* p = fin + ((size_t)b * DU + dr * 100 + su) * 128 + cc * 8;
            float4 f0 = *(const float4*)p;
            float4 f1 = *(const float4*)(p + 4);
            v.x = pk2(f0.x, f0.y); v.y = pk2(f0.z, f0.w);
            v.z = pk2(f1.x, f1.y); v.w = pk2(f1.z, f1.w);
        }
        int byte = (dd * 18 + uu) * 256 + ((cc * 16) ^ ((uu & 7) << 4));
        *(uint4*)((char*)slab + byte) = v;
    }

    for (int tap = 0; tap < 9; ++tap) {
        int dy = tap / 3, dx = tap % 3;
        __syncthreads();                             // prior reads of wl done
        for (int i = tid; i < 2048; i += 256) {      // stage W[tap]: 16B chunks
            int k = i >> 4, cc = i & 15;
            uint4 v = *(const uint4*)(wfb + ((size_t)tap * 128 + k) * 128 + cc * 8);
            int byte = k * 256 + ((cc * 16) ^ ((k & 7) << 4));
            *(uint4*)((char*)wl + byte) = v;
        }
        __syncthreads();
        int uu = l15 + dx;
        int ddr = w + dy;
        int arow = (ddr * 18 + uu) * 256;
        int aswz = (uu & 7) << 4;
#pragma unroll
        for (int cs = 0; cs < 4; ++cs) {
            int cbyte = (cs * 32 + lg * 8) * 2;
            bfv8 a = *(const bfv8*)((const char*)slab + arow + (cbyte ^ aswz));
#pragma unroll
            for (int n = 0; n < 8; ++n) {
                int k = n * 16 + l15;
                bfv8 bq = *(const bfv8*)((const char*)wl + k * 256 + (cbyte ^ ((k & 7) << 4)));
                acc[n] = __builtin_amdgcn_mfma_f32_16x16x32_bf16(a, bq, acc[n], 0, 0, 0);
            }
        }
    }
    int d = d0 + w;
#pragma unroll
    for (int n = 0; n < 8; ++n) {
        int k = n * 16 + l15;
        float bias = bf[k];
#pragma unroll
        for (int r = 0; r < 4; ++r) {
            int u = u0 + lg * 4 + r;
            if (u < 100)
                fout[((size_t)b * DU + d * 100 + u) * 128 + k] =
                    fmaxf(acc[n][r] + bias, 0.f);
        }
    }
}

// ---------------------------------------------------------------------------
// out[b][k2][d][u] = sigmoid(bf3[k2] + sum_c f2[b][du][c]*wf3[k2][c])
__global__ void kHead(const float* __restrict__ f2, const float* __restrict__ wf3,
                      const float* __restrict__ bf3, float* __restrict__ out) {
    int gid = blockIdx.x * blockDim.x + threadIdx.x;
    if (gid >= B * DU) return;
    int b  = gid / DU;
    int du = gid % DU;
    const float* fp = f2 + (size_t)gid * 128;
    float d0 = 0.f, d1 = 0.f;
    for (int c = 0; c < 128; ++c) {
        float v = fp[c];
        d0 = fmaf(v, wf3[c], d0);
        d1 = fmaf(v, wf3[128 + c], d1);
    }
    d0 += bf3[0];
    d1 += bf3[1];
    out[((size_t)b * 2 + 0) * DU + du] = 1.f / (1.f + expf(-d0));
    out[((size_t)b * 2 + 1) * DU + du] = 1.f / (1.f + expf(-d1));
}

// ---------------------------------------------------------------------------
extern "C" void kernel_launch(void* const* d_in, const int* in_sizes, int n_in,
                              void* d_out, int out_size, void* d_ws, size_t ws_size,
                              hipStream_t stream) {
    const float* x    = (const float*)d_in[0];
    const float* wrd  = (const float*)d_in[1];
    const float* brd  = (const float*)d_in[2];
    const float* w3d  = (const float*)d_in[3];
    const float* b3d  = (const float*)d_in[4];
    const float* w2d  = (const float*)d_in[5];
    const float* b2d  = (const float*)d_in[6];
    const float* wf1  = (const float*)d_in[7];
    const float* bf1  = (const float*)d_in[8];
    const float* wf2  = (const float*)d_in[9];
    const float* bf2  = (const float*)d_in[10];
    const float* wf3  = (const float*)d_in[11];
    const float* bf3  = (const float*)d_in[12];
    const float* mask = (const float*)d_in[13];

    float* ws = (float*)d_ws;
    // layout (float-unit offsets); total 21,430,272 f = 85.7 MB
    us* hT    = (us*)(ws + 0);            //    65,536 us -> f [0, 32768)
    us* w3B   = (us*)(ws + 32768);        // 2,097,152 us -> [32768, 1081344)
    us* w2b   = (us*)(ws + 1081344);      //    65,536 us -> [.., 1114112)
    us* wfb1  = (us*)(ws + 1114112);      //   147,456 us -> [.., 1187840)
    us* wfb2  = (us*)(ws + 1187840);      //   147,456 us -> [.., 1261568)
    us* QT    = (us*)(ws + 1261568);      // 8,388,608 us -> [.., 5455872)
    us* maskW = (us*)(ws + 5455872);      // 11,468,800 us -> [.., 11190272)
    float* m2L = ws + 5455872;            // alias maskW (dead after kM3m): 5,120,000 f
    us* m3b   = (us*)(ws + 11190272);     // 20,480,000 us -> [.., 21430272)
    float* f1  = ws + 11190272;           // alias m3b (dead after kM2m)
    float* f2  = ws + 16310272;           // alias m3b second half

    kTransW3B<<<8192, 256, 0, stream>>>(w3d, w3B);
    kTransW2B<<<256, 256, 0, stream>>>(w2d, w2b);
    kTransWfB<<<576, 256, 0, stream>>>(wf1, wfb1);
    kTransWfB<<<576, 256, 0, stream>>>(wf2, wfb2);
    kConv1d<<<B * C1, 128, 0, stream>>>(x, wrd, brd, hT);
    kMaskW<<<11200, 128, 0, stream>>>(mask, maskW);
    kQm<<<256, 256, 0, stream>>>(w3B, hT, QT);
    kM3m<<<1400, 256, 0, stream>>>(maskW, QT, b3d, m3b);
    kM2m<<<B * 157, 256, 0, stream>>>(m3b, w2b, b2d, m2L);
    kConvM<<<B * 25 * 7, 256, 0, stream>>>(m2L, wfb1, bf1, f1);
    kConvM<<<B * 25 * 7, 256, 0, stream>>>(f1, wfb2, bf2, f2);
    kHead<<<(B * DU + 255) / 256, 256, 0, stream>>>(f2, wf3, bf3, (float*)d_out);
}